// Round 9
// baseline (83.138 us; speedup 1.0000x reference)
//
#include <hip/hip_runtime.h>
#include <hip/hip_fp16.h>

// PCEN single-pass block-cooperative chunked scan, v2 (more waves, shorter phases).
//   Block = 512 threads = (b, 512-step segment). Thread (j in [0,16), cg in [0,32)).
//   Phase A: j scans warm sub-chunk [t0-256+16j, +16) zero-init -> Bw[j][cg].
//   Phase B1: j scans main chunk [t0+32j, +32) zero-init -> Bm[j][cg],
//             stashing x as fp16 in 64 registers (full unroll, static idx).
//   barrier; Phase B2: affine fold h = A*h + B (A = 0.96^16 / 0.96^32) from
//   block-boundary init x[t0-256] (residual 0.96^256 ~ 3e-5), then replay
//   the chunk from registers and emit outputs (float4 nontemporal).
// Traffic = 1.5x read (201 MB, warm overlaps neighbor's main -> L2/L3 hits)
// + 1x write (134 MB), all 16 B/lane. 4096 waves = 4/SIMD, 2 blocks/CU.

#define S_COEF 0.04f
#define OMS    0.96f
#define FLOOR_EPS 1e-6f

constexpr int B_DIM = 64;
constexpr int T_DIM = 4096;
constexpr int C_DIM = 128;
constexpr int CG    = C_DIM / 4;   // 32 float4 channel-groups
constexpr int NJ    = 16;          // sub-chunks per block
constexpr int CHUNK = 32;          // timesteps per thread (main)
constexpr int TB    = NJ * CHUNK;  // 512 timesteps per block
constexpr int WSUB  = 16;          // warm sub-chunk per thread
constexpr int WARM  = NJ * WSUB;   // 256 warm steps per block
constexpr int NSEG  = T_DIM / TB;  // 8 segments
constexpr float A_W = 0.52040290f; // 0.96^16
constexpr float A_M = 0.27081921f; // 0.96^32

typedef float f32x4_t __attribute__((ext_vector_type(4)));

__device__ __forceinline__ void nt_store4(const float4& v, float4* p) {
  f32x4_t tmp;
  tmp.x = v.x; tmp.y = v.y; tmp.z = v.z; tmp.w = v.w;
  __builtin_nontemporal_store(tmp, (f32x4_t*)p);
}

__device__ __forceinline__ float pcen_pt(float xv, float h, float a, float d,
                                         float oor, float droot) {
  const float e     = FLOOR_EPS + h;
  const float scale = __expf(-a * __logf(e));      // (floor+ema)^-alpha
  const float base  = fmaf(xv, scale, d);
  return __expf(oor * __logf(base)) - droot;
}

__global__ __launch_bounds__(512, 4) void pcen_fused(
    const float* __restrict__ x,
    const float* __restrict__ alpha,
    const float* __restrict__ delta,
    const float* __restrict__ root,
    float* __restrict__ out) {
  __shared__ float4 Bw[NJ][CG];
  __shared__ float4 Bm[NJ][CG];

  const int cg  = threadIdx.x & (CG - 1);
  const int j   = threadIdx.x >> 5;          // [0,16)
  const int seg = blockIdx.x & (NSEG - 1);
  const int b   = blockIdx.x >> 3;
  const int t0  = seg * TB;

  const float4* __restrict__ xb = (const float4*)x + (size_t)b * T_DIM * CG + cg;

  // ---- Phase A: warm sub-chunk local EMA tail (skip for seg 0) ----
  if (seg) {
    const float4* __restrict__ xw = xb + (size_t)(t0 - WARM + j * WSUB) * CG;
    float4 p = {0.f, 0.f, 0.f, 0.f};
    #pragma unroll
    for (int i = 0; i < WSUB; ++i) {
      const float4 xv = xw[(size_t)i * CG];
      p.x = fmaf(OMS, p.x, S_COEF * xv.x);
      p.y = fmaf(OMS, p.y, S_COEF * xv.y);
      p.z = fmaf(OMS, p.z, S_COEF * xv.z);
      p.w = fmaf(OMS, p.w, S_COEF * xv.w);
    }
    Bw[j][cg] = p;
  }

  // ---- Phase B1: main chunk local EMA tail + stash x as fp16 in regs ----
  const float4* __restrict__ xm = xb + (size_t)(t0 + j * CHUNK) * CG;
  __half2 xsA[CHUNK];  // channels 0,1 of this thread's float4
  __half2 xsB[CHUNK];  // channels 2,3
  float4 q = {0.f, 0.f, 0.f, 0.f};
  #pragma unroll
  for (int i = 0; i < CHUNK; ++i) {
    const float4 xv = xm[(size_t)i * CG];
    xsA[i] = __floats2half2_rn(xv.x, xv.y);
    xsB[i] = __floats2half2_rn(xv.z, xv.w);
    q.x = fmaf(OMS, q.x, S_COEF * xv.x);
    q.y = fmaf(OMS, q.y, S_COEF * xv.y);
    q.z = fmaf(OMS, q.z, S_COEF * xv.z);
    q.w = fmaf(OMS, q.w, S_COEF * xv.w);
  }
  Bm[j][cg] = q;

  __syncthreads();

  // ---- Phase B2: fold boundaries, replay from registers, emit ----
  const float4 al = ((const float4*)alpha)[cg];
  const float4 de = ((const float4*)delta)[cg];
  const float4 ro = ((const float4*)root)[cg];
  const float a0 = fminf(al.x, 1.f), a1 = fminf(al.y, 1.f),
              a2 = fminf(al.z, 1.f), a3 = fminf(al.w, 1.f);
  const float o0 = 1.f / fmaxf(ro.x, 1.f), o1 = 1.f / fmaxf(ro.y, 1.f),
              o2 = 1.f / fmaxf(ro.z, 1.f), o3 = 1.f / fmaxf(ro.w, 1.f);
  const float dr0 = __expf(o0 * __logf(de.x)), dr1 = __expf(o1 * __logf(de.y)),
              dr2 = __expf(o2 * __logf(de.z)), dr3 = __expf(o3 * __logf(de.w));

  float4 h;
  if (seg) {
    h = xb[(size_t)(t0 - WARM) * CG];        // warm-window init (approx, 3e-5)
    #pragma unroll
    for (int k = 0; k < NJ; ++k) {
      const float4 Bk = Bw[k][cg];
      h.x = fmaf(A_W, h.x, Bk.x); h.y = fmaf(A_W, h.y, Bk.y);
      h.z = fmaf(A_W, h.z, Bk.z); h.w = fmaf(A_W, h.w, Bk.w);
    }
  } else {
    h = xb[0];                               // exact: h[-1] = x[0]
  }
  for (int k = 0; k < j; ++k) {              // exact within-block prefix
    const float4 Bk = Bm[k][cg];
    h.x = fmaf(A_M, h.x, Bk.x); h.y = fmaf(A_M, h.y, Bk.y);
    h.z = fmaf(A_M, h.z, Bk.z); h.w = fmaf(A_M, h.w, Bk.w);
  }

  float4* __restrict__ op =
      (float4*)out + ((size_t)b * T_DIM + t0 + j * CHUNK) * CG + cg;
  #pragma unroll
  for (int i = 0; i < CHUNK; ++i) {
    const float2 lo = __half22float2(xsA[i]);
    const float2 hi = __half22float2(xsB[i]);
    h.x = fmaf(OMS, h.x, S_COEF * lo.x);
    h.y = fmaf(OMS, h.y, S_COEF * lo.y);
    h.z = fmaf(OMS, h.z, S_COEF * hi.x);
    h.w = fmaf(OMS, h.w, S_COEF * hi.y);
    float4 o;
    o.x = pcen_pt(lo.x, h.x, a0, de.x, o0, dr0);
    o.y = pcen_pt(lo.y, h.y, a1, de.y, o1, dr1);
    o.z = pcen_pt(hi.x, h.z, a2, de.z, o2, dr2);
    o.w = pcen_pt(hi.y, h.w, a3, de.w, o3, dr3);
    nt_store4(o, op + (size_t)i * CG);
  }
}

extern "C" void kernel_launch(void* const* d_in, const int* in_sizes, int n_in,
                              void* d_out, int out_size, void* d_ws, size_t ws_size,
                              hipStream_t stream) {
  const float* x     = (const float*)d_in[0];
  const float* alpha = (const float*)d_in[1];
  const float* delta = (const float*)d_in[2];
  const float* root  = (const float*)d_in[3];
  float* out = (float*)d_out;

  const int nblocks = B_DIM * NSEG;  // 512 blocks x 512 threads
  pcen_fused<<<nblocks, 512, 0, stream>>>(x, alpha, delta, root, out);
}